// Round 8
// baseline (110.140 us; speedup 1.0000x reference)
//
#include <hip/hip_runtime.h>
#include <hip/hip_bf16.h>
#include <math.h>

#define T_LEN   7680
#define NSEG    59
#define NBINS   45

using bf16x8 = __attribute__((ext_vector_type(8))) short;
using f32x4  = __attribute__((ext_vector_type(4))) float;

__device__ __forceinline__ unsigned f2bf(float f) {
    unsigned u = __builtin_bit_cast(unsigned, f);
    return (u + 0x7FFFu + ((u >> 16) & 1u)) >> 16;   // RNE fp32->bf16
}

// Basis table mt[96][256] bf16, GEMM runs on RAW x (detrend+window folded in):
//   col j=2i   : w_n*cos(2pi(i+1)n/256)      (i=0..44)
//   col j=2i+1 : -w_n*sin(2pi(i+1)n/256)
//   col 0 ALSO adds +0.25: exact detrend correction for k=1 real part, since
//   FFT_k(w*(x-mu)) = A_k - mu*W_k, W_1=-64, mu=S/256 -> Y1re = A1re + S/4.
//   All other bins unaffected by detrend (W_k=0 for |k|>=2; Im W_1 = 0).
__global__ void build_basis_kernel(unsigned short* __restrict__ mt) {
    int j = blockIdx.x, n = threadIdx.x;
    const float TH = 0.02454369260617026f;           // 2*pi/256
    float w = 0.5f - 0.5f * cosf((float)n * TH);     // periodic hann
    float v = 0.f;
    if (j < 90) {
        int k = (j >> 1) + 1;
        int m = (k * n) & 255;                       // exact periodic reduction
        float th = (float)m * TH;
        v = (j & 1) ? (-w * sinf(th)) : (w * cosf(th));
        if (j == 0) v += 0.25f;                      // fold detrend into k=1 re
    }
    mt[j * 256 + n] = (unsigned short)f2bf(v);
}

// R6 structure with ONE change: B-fragments are STREAMED per-rowtile from the
// L2/L3-hot mt table instead of hoisted into 64 VGPRs for the whole kernel.
// Per-rt base pointers are laundered through empty asm to block CSE/LICM from
// re-merging the (identical) loads across rt, which would recreate the hoist.
// Live set in phase G: bA16+bB16+a32+acc32+addr ~= 110 < 128 -> lb(256,4) caps
// above natural demand (R6's spill disaster was cap << demand=145).
// Bisect history: guards NEVER inside the k0 MFMA loop (R3-R5, absmax 4.2e-3).
// R7: never hold prefetch registers across phase G (32 VGPR -> 76MB spills).
__global__ __launch_bounds__(256, 4)
void welch_main_kernel(const float* __restrict__ x,
                       const unsigned short* __restrict__ mt,
                       float* __restrict__ out) {
    __shared__ __align__(16) unsigned short Sm[64 * 256];  // 32 KB, swizzled rows
    __shared__ float psum[96];

    const int tid  = threadIdx.x;
    const int lane = tid & 63;
    const int w    = tid >> 6;
    const int ch   = blockIdx.x;
    const float* gx = x + (size_t)ch * T_LEN;

    // Wave w owns MFMA pairs p=6w..6w+5, p = ct*4 + rt; ctA=(6w)>>2, ctB=(6w+5)>>2.
    const int ctA = (6 * w) >> 2;
    const int ctB = (6 * w + 5) >> 2;
    const int col0 = lane & 15;
    const int kq   = (lane >> 4) * 8;
    const unsigned short* mtA = mt + (ctA * 16 + col0) * 256 + kq;
    const unsigned short* mtB = mt + (ctB * 16 + col0) * 256 + kq;

    if (tid < 96) psum[tid] = 0.f;

    // ---- phase S (R2/R6-verbatim): raw x -> bf16 segments, XOR-swizzled rows.
    // chunk c covers x[4c..4c+3]; half hh=c>>5 is first half of seg hh and
    // second half of seg hh-1 -> one global read serves both LDS writes.
    #pragma unroll
    for (int i = 0; i < 8; ++i) {
        int c = i * 256 + tid;
        if (c < 1920) {
            f32x4 xv = *reinterpret_cast<const f32x4*>(gx + 4 * c);
            unsigned b0 = f2bf(xv[0]), b1 = f2bf(xv[1]);
            unsigned b2 = f2bf(xv[2]), b3 = f2bf(xv[3]);
            uint2 pk; pk.x = b0 | (b1 << 16); pk.y = b2 | (b3 << 16);
            int hh = c >> 5, q = c & 31;
            if (hh < NSEG) {
                unsigned a = (unsigned)(hh * 512 + 8 * q) ^ (unsigned)((hh & 7) << 4);
                *reinterpret_cast<uint2*>((char*)Sm + a) = pk;
            }
            if (hh > 0) {
                int s = hh - 1;
                unsigned a = (unsigned)(s * 512 + 256 + 8 * q) ^ (unsigned)((s & 7) << 4);
                *reinterpret_cast<uint2*>((char*)Sm + a) = pk;
            }
        }
    }
    // zero-pad rows 59..63 (read by rowtile 3)
    for (int z = tid; z < 320; z += 256) {
        int row = 59 + (z >> 6), q = z & 63;
        unsigned a = (unsigned)(row * 512 + 8 * q) ^ (unsigned)((row & 7) << 4);
        *reinterpret_cast<uint2*>((char*)Sm + a) = make_uint2(0u, 0u);
    }
    __syncthreads();

    // ---- phase G: 6 (ct,rt) pairs per wave; B-frags streamed per rt.
    f32x4 accA[4], accB[4];
    #pragma unroll
    for (int r = 0; r < 4; ++r) {
        accA[r] = (f32x4){0.f, 0.f, 0.f, 0.f};
        accB[r] = (f32x4){0.f, 0.f, 0.f, 0.f};
    }
    const unsigned kq16 = (unsigned)((lane >> 4) * 16);
    #pragma unroll
    for (int rt = 0; rt < 4; ++rt) {
        // launder base pointers: blocks CSE/LICM across rt (keeps live set low)
        const unsigned short* pA_ = mtA;
        const unsigned short* pB_ = mtB;
        asm volatile("" : "+v"(pA_), "+v"(pB_));
        bf16x8 bA[8], bB[8];
        #pragma unroll
        for (int k0 = 0; k0 < 8; ++k0) {
            bA[k0] = *reinterpret_cast<const bf16x8*>(pA_ + k0 * 32);
            bB[k0] = *reinterpret_cast<const bf16x8*>(pB_ + k0 * 32);
        }
        const int arow = rt * 16 + (lane & 15);
        const unsigned abase = (unsigned)arow * 512u;
        const unsigned aswz  = (unsigned)((arow & 7) << 4);
        bf16x8 a[8];
        #pragma unroll
        for (int k0 = 0; k0 < 8; ++k0)
            a[k0] = *reinterpret_cast<const bf16x8*>(
                (char*)Sm + ((abase + (unsigned)k0 * 64u + kq16) ^ aswz));
        const bool oA = (unsigned)(ctA * 4 + rt - 6 * w) < 6u;
        const bool oB = (unsigned)(ctB * 4 + rt - 6 * w) < 6u;
        if (oA) {
            #pragma unroll
            for (int k0 = 0; k0 < 8; ++k0)
                accA[rt] = __builtin_amdgcn_mfma_f32_16x16x32_bf16(
                    a[k0], bA[k0], accA[rt], 0, 0, 0);
        }
        if (oB && ctB != ctA) {
            #pragma unroll
            for (int k0 = 0; k0 < 8; ++k0)
                accB[rt] = __builtin_amdgcn_mfma_f32_16x16x32_bf16(
                    a[k0], bB[k0], accB[rt], 0, 0, 0);
        }
    }

    // ---- phase E (R2/R6-verbatim): colsum of acc^2 per owned ct.
    // C/D layout: col = lane&15, row = rt*16 + (lane>>4)*4 + reg.
    {
        float pA = 0.f, pB = 0.f;
        #pragma unroll
        for (int rt = 0; rt < 4; ++rt) {
            if ((unsigned)(ctA * 4 + rt - 6 * w) < 6u)
                pA += accA[rt][0]*accA[rt][0] + accA[rt][1]*accA[rt][1]
                    + accA[rt][2]*accA[rt][2] + accA[rt][3]*accA[rt][3];
            if ((unsigned)(ctB * 4 + rt - 6 * w) < 6u && ctB != ctA)
                pB += accB[rt][0]*accB[rt][0] + accB[rt][1]*accB[rt][1]
                    + accB[rt][2]*accB[rt][2] + accB[rt][3]*accB[rt][3];
        }
        pA += __shfl_xor(pA, 16);  pA += __shfl_xor(pA, 32);
        pB += __shfl_xor(pB, 16);  pB += __shfl_xor(pB, 32);
        if (lane < 16) {
            atomicAdd(&psum[ctA * 16 + col0], pA);
            if (ctB != ctA) atomicAdd(&psum[ctB * 16 + col0], pB);
        }
    }
    __syncthreads();

    // ---- output: psd_k = (re^2+im^2 summed)*2/(fs*sum(w^2)*nseg); log1p
    if (tid < NBINS) {
        const float CNORM = 2.0f / (24576.0f * 59.0f);  // fs*sum(w^2) = 256*96
        float psd = (psum[2 * tid] + psum[2 * tid + 1]) * CNORM;
        out[(size_t)ch * NBINS + tid] = log1pf(psd);
    }
}

extern "C" void kernel_launch(void* const* d_in, const int* in_sizes, int n_in,
                              void* d_out, int out_size, void* d_ws, size_t ws_size,
                              hipStream_t stream) {
    const float* x = (const float*)d_in[0];
    float* out = (float*)d_out;
    unsigned short* mt = (unsigned short*)d_ws;   // 96*256*2 = 49152 B

    build_basis_kernel<<<96, 256, 0, stream>>>(mt);
    welch_main_kernel<<<4096, 256, 0, stream>>>(x, mt, out);
}

// Round 9
// 63.451 us; speedup vs baseline: 1.7358x; 1.7358x over previous
//
#include <hip/hip_runtime.h>
#include <hip/hip_bf16.h>
#include <math.h>

#define T_LEN   7680
#define NSEG    59
#define NBINS   45

using bf16x8 = __attribute__((ext_vector_type(8))) short;
using f32x4  = __attribute__((ext_vector_type(4))) float;

__device__ __forceinline__ unsigned f2bf(float f) {
    unsigned u = __builtin_bit_cast(unsigned, f);
    return (u + 0x7FFFu + ((u >> 16) & 1u)) >> 16;   // RNE fp32->bf16
}

// Pure-address-function LDS swizzle (same function on write and read side by
// construction -> self-consistent). Spreads 256B-strided rows across 8
// distinct 16B slots; preserves 16B-block contiguity (bits 0-3 untouched).
__device__ __forceinline__ unsigned phys(unsigned a) {
    return a ^ (((a >> 8) & 7u) << 4);
}

// Basis table mt[96][256] bf16, GEMM runs on RAW x (detrend+window folded in):
//   col j=2i   : w_n*cos(2pi(i+1)n/256)      (i=0..44)
//   col j=2i+1 : -w_n*sin(2pi(i+1)n/256)
//   col 0 ALSO adds +0.25: exact detrend correction for k=1 real part, since
//   FFT_k(w*(x-mu)) = A_k - mu*W_k, W_1=-64, mu=S/256 -> Y1re = A1re + S/4.
//   All other bins unaffected by detrend (W_k=0 for |k|>=2; Im W_1 = 0).
__global__ void build_basis_kernel(unsigned short* __restrict__ mt) {
    int j = blockIdx.x, n = threadIdx.x;
    const float TH = 0.02454369260617026f;           // 2*pi/256
    float w = 0.5f - 0.5f * cosf((float)n * TH);     // periodic hann
    float v = 0.f;
    if (j < 90) {
        int k = (j >> 1) + 1;
        int m = (k * n) & 255;                       // exact periodic reduction
        float th = (float)m * TH;
        v = (j & 1) ? (-w * sinf(th)) : (w * cosf(th));
        if (j == 0) v += 0.25f;                      // fold detrend into k=1 re
    }
    mt[j * 256 + n] = (unsigned short)f2bf(v);
}

// R2/R6-proven structure with two register/LDS diet changes:
//  (1) non-duplicated LDS layout xs[8320] (17.4 KB, phys() swizzle): one LDS
//      write per chunk instead of two; segment row s = bytes s*256..s*256+511.
//  (2) per-rt square-sum fold: acc lives only within one rt (8 regs, not 32).
//      Bitwise-identical summation order vs R2's separate phase E.
// Ledger: breg stays HOISTED (R8: streaming it added 4x300cy to the critical
// path -> 110us). Guards stay OUTSIDE the k0 MFMA loop (R3-R5: absmax 4.2e-3).
// No prefetch regs held across G (R7: 76MB spills). lb is a floor, not a cap
// (R6: lb4 squeezed 144->64 VGPR -> 20MB spills); target is NATURAL <=128.
__global__ __launch_bounds__(256, 3)
void welch_main_kernel(const float* __restrict__ x,
                       const unsigned short* __restrict__ mt,
                       float* __restrict__ out) {
    __shared__ __align__(16) unsigned short xs[8320];  // 16640 B
    __shared__ float psum[96];

    const int tid  = threadIdx.x;
    const int lane = tid & 63;
    const int w    = tid >> 6;
    const int ch   = blockIdx.x;
    const float* gx = x + (size_t)ch * T_LEN;

    // ---- B fragments (R2-verbatim hoist): wave w owns pairs p=6w..6w+5,
    // p = ct*4 + rt; ctA=(6w)>>2, ctB=(6w+5)>>2 (always distinct).
    const int ctA = (6 * w) >> 2;
    const int ctB = (6 * w + 5) >> 2;
    const int col0 = lane & 15;
    const int kq   = (lane >> 4) * 8;
    bf16x8 bregA[8], bregB[8];
    #pragma unroll
    for (int k0 = 0; k0 < 8; ++k0) {
        bregA[k0] = *reinterpret_cast<const bf16x8*>(
            mt + (ctA * 16 + col0) * 256 + k0 * 32 + kq);
        bregB[k0] = *reinterpret_cast<const bf16x8*>(
            mt + (ctB * 16 + col0) * 256 + k0 * 32 + kq);
    }

    if (tid < 96) psum[tid] = 0.f;

    // ---- phase S: raw x -> bf16, ONE swizzled 8B write per chunk.
    #pragma unroll
    for (int i = 0; i < 8; ++i) {
        int c = i * 256 + tid;
        if (c < 1920) {
            f32x4 xv = *reinterpret_cast<const f32x4*>(gx + 4 * c);
            unsigned b0 = f2bf(xv[0]), b1 = f2bf(xv[1]);
            unsigned b2 = f2bf(xv[2]), b3 = f2bf(xv[3]);
            uint2 pk; pk.x = b0 | (b1 << 16); pk.y = b2 | (b3 << 16);
            *reinterpret_cast<uint2*>((char*)xs + phys((unsigned)c * 8u)) = pk;
        }
    }
    // zero-pad samples 7680..8319 (rows 59..63 tail reads)
    if (tid < 160) {
        unsigned a = phys(15360u + (unsigned)tid * 8u);
        *reinterpret_cast<uint2*>((char*)xs + a) = make_uint2(0u, 0u);
    }
    __syncthreads();

    // ---- phase G (R2 shape: a[8] array, guards OUTSIDE the k0 loop) with
    // per-rt square-sum fold. Rows 59..63 windows: real samples + zero pad;
    // their acc outputs ARE included -- wait, they must be EXCLUDED.
    // They are: zero-pad makes rows 59..63 equal to (real tail + zeros),
    // which is NOT a valid segment -> mask their contribution in the fold.
    float pA = 0.f, pB = 0.f;
    const unsigned kq16 = (unsigned)((lane >> 4) * 16);
    #pragma unroll
    for (int rt = 0; rt < 4; ++rt) {
        const unsigned abase = (unsigned)(rt * 16 + (lane & 15)) * 256u;
        bf16x8 a[8];
        #pragma unroll
        for (int k0 = 0; k0 < 8; ++k0)
            a[k0] = *reinterpret_cast<const bf16x8*>(
                (char*)xs + phys(abase + (unsigned)k0 * 64u + kq16));
        f32x4 accA = (f32x4){0.f, 0.f, 0.f, 0.f};
        f32x4 accB = (f32x4){0.f, 0.f, 0.f, 0.f};
        const bool oA = (unsigned)(ctA * 4 + rt - 6 * w) < 6u;
        const bool oB = (unsigned)(ctB * 4 + rt - 6 * w) < 6u;
        if (oA) {
            #pragma unroll
            for (int k0 = 0; k0 < 8; ++k0)
                accA = __builtin_amdgcn_mfma_f32_16x16x32_bf16(
                    a[k0], bregA[k0], accA, 0, 0, 0);
        }
        if (oB) {
            #pragma unroll
            for (int k0 = 0; k0 < 8; ++k0)
                accB = __builtin_amdgcn_mfma_f32_16x16x32_bf16(
                    a[k0], bregB[k0], accB, 0, 0, 0);
        }
        // C/D layout: col = lane&15, row = rt*16 + (lane>>4)*4 + r.
        // Mask junk rows 59..63 (only possible at rt==3).
        const int rowbase = rt * 16 + (lane >> 4) * 4;
        #pragma unroll
        for (int r = 0; r < 4; ++r) {
            if (rt < 3 || rowbase + r < NSEG) {
                pA += accA[r] * accA[r];
                pB += accB[r] * accB[r];
            }
        }
    }

    // ---- phase E reduce (R2-verbatim): over row-groups, then LDS atomics
    pA += __shfl_xor(pA, 16);  pA += __shfl_xor(pA, 32);
    pB += __shfl_xor(pB, 16);  pB += __shfl_xor(pB, 32);
    if (lane < 16) {
        atomicAdd(&psum[ctA * 16 + col0], pA);
        atomicAdd(&psum[ctB * 16 + col0], pB);
    }
    __syncthreads();

    // ---- output: psd_k = (re^2+im^2 summed)*2/(fs*sum(w^2)*nseg); log1p
    if (tid < NBINS) {
        const float CNORM = 2.0f / (24576.0f * 59.0f);  // fs*sum(w^2) = 256*96
        float psd = (psum[2 * tid] + psum[2 * tid + 1]) * CNORM;
        out[(size_t)ch * NBINS + tid] = log1pf(psd);
    }
}

extern "C" void kernel_launch(void* const* d_in, const int* in_sizes, int n_in,
                              void* d_out, int out_size, void* d_ws, size_t ws_size,
                              hipStream_t stream) {
    const float* x = (const float*)d_in[0];
    float* out = (float*)d_out;
    unsigned short* mt = (unsigned short*)d_ws;   // 96*256*2 = 49152 B

    build_basis_kernel<<<96, 256, 0, stream>>>(mt);
    welch_main_kernel<<<4096, 256, 0, stream>>>(x, mt, out);
}